// Round 11
// baseline (882.590 us; speedup 1.0000x reference)
//
#include <hip/hip_runtime.h>
#include <hip/hip_bf16.h>
#include <cstdint>

#define KDIM 512
#define BM 128
#define BN 128
#define BK 64
#define M_MAIN 100352   // 512*196
#define NPIX 196
#define BATCH 512

typedef float f32x4 __attribute__((ext_vector_type(4)));
typedef short s16x8 __attribute__((ext_vector_type(8)));

__device__ __forceinline__ short f2bf(float f) {
    uint32_t u = __float_as_uint(f);
    uint32_t r = u + 0x7FFFu + ((u >> 16) & 1u);   // round-to-nearest-even
    return (short)(r >> 16);
}

__device__ __forceinline__ void gload_lds16(const void* g, void* l) {
    __builtin_amdgcn_global_load_lds(
        (const __attribute__((address_space(1))) void*)g,
        (__attribute__((address_space(3))) void*)l, 16, 0, 0);
}

__device__ __forceinline__ uint32_t pkbf(float lo, float hi) {
    __hip_bfloat162 p = __float22bfloat162_rn(float2{lo, hi});
    return *reinterpret_cast<uint32_t*>(&p);
}

// Transpose + convert W [K][A] fp32 -> Wt [A][K] bf16 for both weight matrices.
__global__ void prep_w(const float* __restrict__ W_enc, const float* __restrict__ W_dec,
                       short* __restrict__ Wt_enc, short* __restrict__ Wt_dec) {
    int a = blockIdx.x;
    int k = threadIdx.x;
    const float* W = blockIdx.y ? W_dec : W_enc;
    short* Wt = blockIdx.y ? Wt_dec : Wt_enc;
    Wt[a * KDIM + k] = f2bf(W[(size_t)k * KDIM + a]);
}

__global__ void zero_cnt(int* cnt) { cnt[threadIdx.x] = 0; }

// R3's verified GEMM (best bench: 150.9us) + fused completion-counted
// softmax/context epilogue.
// 512 threads = 8 waves as 2(M) x 4(N); per-wave output 64x32 (acc[4][2]).
// LDS tiles XOR-swizzled: 16B slot s of row r holds logical slot s^(r&7);
// B staged via global_load_lds -> global SOURCE column pre-swizzled (rule #21).
// EPI==0: out[row][col] = acc + b1[col] + b2[col]        (att_dec' precompute)
// EPI==1: energy partial per column-block written to outp[bx*M+row]; then each
//         block atomicAdds a per-batch counter (target = 4 slices x covering
//         row-blocks); the block making the final increment runs softmax +
//         context for that batch inline (deterministic: reads only completed
//         partials; value independent of arrival order).
template <int EPI>
__launch_bounds__(512, 4)
__global__ void gemm_fused(const float* __restrict__ A, int M,
                           const short* __restrict__ Bt,
                           const float* __restrict__ b1, const float* __restrict__ b2,
                           const float* __restrict__ attdec, const float* __restrict__ wfull,
                           float* __restrict__ outp,
                           int* __restrict__ cnt, float* __restrict__ finalout) {
    __shared__ short lds_a[2][BM][BK];
    __shared__ short lds_b[2][BN][BK];
    __shared__ float swred[8];
    __shared__ int winfl[2];

    const int tid = threadIdx.x;
    const int wave = tid >> 6;
    const int lane = tid & 63;
    const int wm = wave >> 2;       // 2 waves along M
    const int wn = wave & 3;        // 4 waves along N
    // XCD-aware bijective swizzle (gridDim.x % 8 == 0 for both instantiations)
    const int nwg = gridDim.x;
    const int q = nwg >> 3;
    const int swzb = (blockIdx.x & 7) * q + (blockIdx.x >> 3);
    const int bx = swzb & 3;        // N/BN = 4 column blocks
    const int by = swzb >> 2;
    const int r0 = by * BM;
    const int c0 = bx * BN;

    f32x4 areg[4];

    auto loadA = [&](int kt) {
#pragma unroll
        for (int j = 0; j < 4; ++j) {
            int f = tid + 512 * j;          // float4 index in 128x64 tile (16 per row)
            int row = f >> 4, c4 = f & 15;
            areg[j] = *(const f32x4*)(A + (size_t)(r0 + row) * KDIM + kt * BK + c4 * 4);
        }
    };
    auto writeA = [&](int buf) {
#pragma unroll
        for (int j = 0; j < 4; ++j) {
            int f = tid + 512 * j;
            int row = f >> 4;
            int cs = (f & 15) * 4;                    // short index in row
            int cw = cs ^ ((row & 7) * 8);            // XOR-swizzle 16B slot
            f32x4 v = areg[j];
            uint2 w;
            w.x = pkbf(v[0], v[1]);
            w.y = pkbf(v[2], v[3]);
            *reinterpret_cast<uint2*>(&lds_a[buf][row][cw]) = w;
        }
    };
    auto stageB = [&](int buf, int kt) {
#pragma unroll
        for (int i = 0; i < 2; ++i) {
            int rb = wave * 16 + i * 8;     // 8 rows per issue (64 lanes * 16B)
            int srcslot = (lane & 7) ^ (lane >> 3);   // pre-swizzle SOURCE (rule #21)
            const short* g = Bt + (size_t)(c0 + rb + (lane >> 3)) * KDIM + kt * BK + srcslot * 8;
            gload_lds16(g, &lds_b[buf][rb][0]);
        }
    };

    f32x4 acc[4][2];
#pragma unroll
    for (int i = 0; i < 4; ++i)
#pragma unroll
        for (int j = 0; j < 2; ++j)
            acc[i][j] = (f32x4){0.f, 0.f, 0.f, 0.f};

    auto compute = [&](int buf) {
#pragma unroll
        for (int kk = 0; kk < 2; ++kk) {
            s16x8 af[4], bf[2];
#pragma unroll
            for (int fm = 0; fm < 4; ++fm) {
                int ra = wm * 64 + fm * 16 + (lane & 15);
                af[fm] = *(const s16x8*)&lds_a[buf][ra][(kk * 32 + (lane >> 4) * 8) ^ ((ra & 7) * 8)];
            }
#pragma unroll
            for (int fn = 0; fn < 2; ++fn) {
                int rb = wn * 32 + fn * 16 + (lane & 15);
                bf[fn] = *(const s16x8*)&lds_b[buf][rb][(kk * 32 + (lane >> 4) * 8) ^ ((rb & 7) * 8)];
            }
#pragma unroll
            for (int fm = 0; fm < 4; ++fm)
#pragma unroll
                for (int fn = 0; fn < 2; ++fn)
                    acc[fm][fn] = __builtin_amdgcn_mfma_f32_16x16x32_bf16(af[fm], bf[fn], acc[fm][fn], 0, 0, 0);
        }
    };

    // Prologue: stage tile 0
    loadA(0);
    stageB(0, 0);
    writeA(0);
    __syncthreads();

    const int nk = KDIM / BK;   // 8
    for (int t = 0; t < nk; ++t) {
        int cur = t & 1;
        if (t + 1 < nk) {
            loadA(t + 1);
            stageB(cur ^ 1, t + 1);
        }
        compute(cur);
        if (t + 1 < nk) writeA(cur ^ 1);
        __syncthreads();
    }

    const int lcol = lane & 15;
    const int lrg = (lane >> 4) * 4;

    if constexpr (EPI == 0) {
#pragma unroll
        for (int fm = 0; fm < 4; ++fm)
#pragma unroll
            for (int fn = 0; fn < 2; ++fn) {
                int col = c0 + wn * 32 + fn * 16 + lcol;
                float bias = b1[col] + b2[col];
#pragma unroll
                for (int reg = 0; reg < 4; ++reg) {
                    int row = r0 + wm * 64 + fm * 16 + lrg + reg;
                    outp[(size_t)row * KDIM + col] = acc[fm][fn][reg] + bias;
                }
            }
    } else {
        float wfv[2];
        int colv[2];
#pragma unroll
        for (int fn = 0; fn < 2; ++fn) {
            colv[fn] = c0 + wn * 32 + fn * 16 + lcol;
            wfv[fn] = wfull[colv[fn]];
        }
        // per-wave partial energies -> LDS (reuse lds_a; safe after loop's final barrier)
        float* ebuf = reinterpret_cast<float*>(lds_a);   // [4 wn][128 rows]
#pragma unroll
        for (int fm = 0; fm < 4; ++fm) {
#pragma unroll
            for (int reg = 0; reg < 4; ++reg) {
                int row = r0 + wm * 64 + fm * 16 + lrg + reg;
                int b = row / NPIX;
                float es = 0.f;
#pragma unroll
                for (int fn = 0; fn < 2; ++fn) {
                    float v = acc[fm][fn][reg] + attdec[(size_t)b * KDIM + colv[fn]];
                    v = fmaxf(v, 0.f);
                    es = fmaf(v, wfv[fn], es);
                }
#pragma unroll
                for (int m = 1; m < 16; m <<= 1) es += __shfl_xor(es, m);
                if (lcol == 0) ebuf[wn * BM + wm * 64 + fm * 16 + lrg + reg] = es;
            }
        }
        __syncthreads();
        if (tid < BM) {
            float s = (ebuf[tid] + ebuf[BM + tid]) + (ebuf[2 * BM + tid] + ebuf[3 * BM + tid]);
            outp[(size_t)bx * M + r0 + tid] = s;
        }
        // ---- completion counting (release: store -> fence -> sync -> atomic) ----
        __threadfence();
        __syncthreads();
        if (tid == 0) {
            winfl[0] = -1; winfl[1] = -1;
            const int bA = r0 / NPIX;
            const int bB = (r0 + BM - 1) / NPIX;
            int k = 0;
            for (int b = bA; b <= bB; ++b, ++k) {
                int lo = (b * NPIX) >> 7;
                int hi = (b * NPIX + NPIX - 1) >> 7;
                int target = 4 * (hi - lo + 1);
                int old = atomicAdd(&cnt[b], 1);
                if (old == target - 1) winfl[k] = b;
            }
        }
        __syncthreads();
#pragma unroll 1
        for (int k = 0; k < 2; ++k) {
            const int b = winfl[k];
            if (b < 0) continue;
            __threadfence();    // acquire side
            // ---- softmax over 196 energies (sum of 4 slice partials) ----
            float e = -1e30f;
            if (tid < NPIX) {
                e = outp[b * NPIX + tid] + outp[(size_t)M + b * NPIX + tid]
                  + outp[2 * (size_t)M + b * NPIX + tid] + outp[3 * (size_t)M + b * NPIX + tid];
            }
            float mx = e;
#pragma unroll
            for (int d = 1; d < 64; d <<= 1) mx = fmaxf(mx, __shfl_xor(mx, d));
            if (lane == 0) swred[wave] = mx;
            __syncthreads();
            mx = swred[0];
#pragma unroll
            for (int i = 1; i < 8; ++i) mx = fmaxf(mx, swred[i]);
            __syncthreads();
            float ex = (tid < NPIX) ? __expf(e - mx) : 0.f;
            float sm = ex;
#pragma unroll
            for (int d = 1; d < 64; d <<= 1) sm += __shfl_xor(sm, d);
            if (lane == 0) swred[wave] = sm;
            __syncthreads();
            sm = swred[0];
#pragma unroll
            for (int i = 1; i < 8; ++i) sm += swred[i];
            float al = ex / sm;
            float* sal = reinterpret_cast<float*>(lds_a);
            if (tid < NPIX) {
                sal[tid] = al;
                finalout[BATCH * KDIM + b * NPIX + tid] = al;
            }
            __syncthreads();
            // ---- context: 512 threads, one column each; coalesced 2KB/row ----
            float c = 0.f;
            const float* eb = A + (size_t)b * NPIX * KDIM;
#pragma unroll 4
            for (int p = 0; p < NPIX; ++p)
                c = fmaf(eb[(size_t)p * KDIM + tid], sal[p], c);
            finalout[(size_t)b * KDIM + tid] = c;
            __syncthreads();
        }
    }
}

extern "C" void kernel_launch(void* const* d_in, const int* in_sizes, int n_in,
                              void* d_out, int out_size, void* d_ws, size_t ws_size,
                              hipStream_t stream) {
    const float* encoder = (const float*)d_in[0];   // [512,196,512]
    const float* dec_h   = (const float*)d_in[1];   // [512,512]
    const float* W_enc   = (const float*)d_in[2];   // [512,512]
    const float* b_enc   = (const float*)d_in[3];   // [512]
    const float* W_dec   = (const float*)d_in[4];   // [512,512]
    const float* b_decv  = (const float*)d_in[5];   // [512]
    const float* w_full  = (const float*)d_in[6];   // [512]
    float* out = (float*)d_out;                     // context [512,512] ++ alpha [512,196]

    short* wt_enc = (short*)d_ws;                   // 512*512 bf16
    short* wt_dec = wt_enc + 512 * 512;             // 512*512 bf16
    float* attdec = (float*)(wt_dec + 512 * 512);   // [512][512] fp32 (incl. both biases)
    float* energy4 = attdec + 512 * 512;            // [4][100352] fp32 slice partials
    int* cnt = (int*)(energy4 + 4 * (size_t)M_MAIN);// [512] completion counters

    // 0) zero per-batch counters (graph-safe, deterministic each call)
    zero_cnt<<<dim3(1), 512, 0, stream>>>(cnt);

    // 1) weight transpose + bf16 convert
    prep_w<<<dim3(512, 2), 512, 0, stream>>>(W_enc, W_dec, wt_enc, wt_dec);

    // 2) att_dec' = dec_h @ W_dec + b_dec + b_enc   (store fp32 [512][512])
    gemm_fused<0><<<dim3(16), 512, 0, stream>>>(dec_h, 512, wt_dec,
                                                b_enc, b_decv, nullptr, nullptr, attdec,
                                                nullptr, nullptr);

    // 3) main fused GEMM -> energy partials; last-finishing block per batch
    //    runs softmax+context inline (tail folded into GEMM window)
    gemm_fused<1><<<dim3(4 * (M_MAIN / BM)), 512, 0, stream>>>(encoder, M_MAIN, wt_enc,
                                                               nullptr, nullptr, attdec, w_full, energy4,
                                                               cnt, out);
}